// Round 13
// baseline (178.301 us; speedup 1.0000x reference)
//
#include <hip/hip_runtime.h>

#define TPB_PACK  256
#define P1_BLOCKS 512
#define P1_TPB    1024
#define SB_BITS   14
#define SBS       (1 << SB_BITS)     // atoms per super-bucket (16384)
#define NS_MAX    16
#define P2_TPB    1024
#define R_SUB     20                 // 13*20=260 blocks; 2 co-residable/CU (128 KB LDS)
#define TPB_RED   256
#define CAP_MAX   1024

// log-spaced energy table: r = 2^(L0 + k*HL), k in [0,256]; 258 entries/type (pad)
#define TAB_N   258
#define TAB_L0  (-3.3219281f)        // log2(0.1)
#define TAB_HL  (0.017157490f)       // (log2(2.1)-log2(0.1))/256
#define TAB_INV (58.283567f)         // 1/TAB_HL
#define TAB_OFF (193.61423f)         // -L0*TAB_INV

// ---- pack atom types (2 bits each) AND zero the fallback accumulator ----
__global__ __launch_bounds__(TPB_PACK) void zbl_pack(
    const int* __restrict__ types, unsigned int* __restrict__ packed,
    float* __restrict__ fallback, int natoms, int nwords)
{
    int tid = blockIdx.x * TPB_PACK + threadIdx.x;
    int nth = gridDim.x * TPB_PACK;
    for (int w = tid; w < nwords; w += nth) {
        int base = w << 4;
        unsigned int word = 0;
        #pragma unroll
        for (int j = 0; j < 16; ++j) {
            int i = base + j;
            unsigned int t = (i < natoms) ? (unsigned int)types[i] : 0u;
            word |= (t & 3u) << (2 * j);
        }
        packed[w] = word;
    }
    for (int i = tid; i < natoms; i += nth) fallback[i] = 0.0f;
}

// ------- Phase 1: tabulated e(r,t); per-lane binning into NS coarse buckets -------
// 4 B records: f32 e with low 14 mantissa bits (rounded away) replaced by the
// atom index within the super-bucket. Exponent untouched -> e!=0 gate and
// in-bucket index both survive; rel err 2^-10.
__global__ __launch_bounds__(P1_TPB) void zbl_bin(
    const float* __restrict__ rij,
    const float* __restrict__ rcov,
    const float* __restrict__ znum,
    const int*  __restrict__ fa,
    const int*  __restrict__ sa,
    const unsigned int* __restrict__ packed,
    unsigned int* __restrict__ regions,  // [P1_BLOCKS][NS][cap] 4 B records
    int*   __restrict__ counts,          // [NS][P1_BLOCKS] (transposed)
    float* __restrict__ fallback,        // natoms floats, pre-zeroed (= d_out if cap==0)
    int E, int nquad, int natoms, int nwords, int NS, int cap, int chunkQ)
{
    extern __shared__ unsigned int s_packed[];   // nwords words (~50 KB)
    __shared__ float  tabE[16 * TAB_N];          // 16.5 KB energy table
    __shared__ float4 cB[16];                    // {rc, f/2, A/6, B/8}
    __shared__ float4 cS[16];                    // exp2 slopes
    __shared__ float  cC[16];                    // C/2
    __shared__ int scnt[NS_MAX];

    for (int w = threadIdx.x; w < nwords; w += P1_TPB)
        s_packed[w] = packed[w];                 // coalesced, L2-resident
    if (threadIdx.x < NS) scnt[threadIdx.x] = 0;

    if (threadIdx.x < 16) {
        const float cc[4] = {0.02817f, 0.28022f, 0.50986f, 0.18175f};
        const float dd[4] = {0.20162f, 0.4029f, 0.94229f, 3.1998f};
        const float COUL = 14.399645478425668f;
        int t = threadIdx.x;
        int ti = t >> 2, tj = t & 3;
        float zi = znum[ti], zj = znum[tj];
        float rc = rcov[ti] + rcov[tj];
        float a = 0.4685f / (powf(zi, 0.23f) + powf(zj, 0.23f));
        float inva = 1.0f / a;
        float factor = COUL * zi * zj;
        float da[4], ee[4];
        float phi = 0.0f, dphi = 0.0f, d2phi = 0.0f;
        #pragma unroll
        for (int k = 0; k < 4; ++k) {
            da[k] = dd[k] * inva;
            ee[k] = expf(-rc * da[k]);
            phi   += cc[k] * ee[k];
            dphi  -= cc[k] * da[k] * ee[k];
            d2phi += cc[k] * da[k] * da[k] * ee[k];
        }
        float invrc = 1.0f / rc;
        float ec   = factor * invrc * phi;
        float dec  = factor * invrc * (-phi * invrc + dphi);
        float d2ec = factor * invrc * (d2phi - 2.0f * invrc * dphi + 2.0f * phi * invrc * invrc);
        float A = (-3.0f * dec + rc * d2ec) * invrc * invrc;
        float B = (2.0f * dec - rc * d2ec) * invrc * invrc * invrc;
        float Cc = -ec + 0.5f * rc * dec - rc * rc * d2ec * (1.0f / 12.0f);
        const float L2E = 1.4426950408889634f;
        cB[t] = make_float4(rc, 0.5f * factor, A * (1.0f / 6.0f), B * 0.125f);
        cS[t] = make_float4(-da[0] * L2E, -da[1] * L2E, -da[2] * L2E, -da[3] * L2E);
        cC[t] = Cc * 0.5f;
    }
    __syncthreads();

    const float lc0 = -5.1497481f;   // log2(0.02817)
    const float lc1 = -1.8353434f;   // log2(0.28022)
    const float lc2 = -0.9718340f;   // log2(0.50986)
    const float lc3 = -2.4600449f;   // log2(0.18175)

    // build the per-type energy table (once per block)
    for (int n = threadIdx.x; n < 16 * TAB_N; n += P1_TPB) {
        int t = n / TAB_N, k = n - t * TAB_N;
        float v = 0.0f;
        if (k <= 256) {
            float r = exp2f(__builtin_fmaf((float)k, TAB_HL, TAB_L0));
            float4 B = cB[t];
            if (r <= B.x) {
                float4 S = cS[t];
                float p = exp2f(__builtin_fmaf(r, S.x, lc0))
                        + exp2f(__builtin_fmaf(r, S.y, lc1))
                        + exp2f(__builtin_fmaf(r, S.z, lc2))
                        + exp2f(__builtin_fmaf(r, S.w, lc3));
                float r3 = r * r * r;
                float poly = __builtin_fmaf(__builtin_fmaf(B.w, r, B.z), r3, cC[t]);
                v = __builtin_fmaf(B.y * p, 1.0f / r, poly);
            }
        }
        tabE[n] = v;
    }
    __syncthreads();

    const float4* rij4 = (const float4*)rij;
    const int4*   fa4  = (const int4*)fa;
    const int4*   sa4  = (const int4*)sa;

    size_t myreg = (size_t)blockIdx.x * NS;

    int q0 = blockIdx.x * chunkQ;
    int q1 = q0 + chunkQ; if (q1 > nquad) q1 = nquad;

    for (int q = q0 + threadIdx.x; q < q1; q += P1_TPB) {
        float4 rv = rij4[q];
        int4   iv = fa4[q];
        int4   jv = sa4[q];
        float ra[4] = {rv.x, rv.y, rv.z, rv.w};
        int   ia[4] = {iv.x, iv.y, iv.z, iv.w};
        int   ja[4] = {jv.x, jv.y, jv.z, jv.w};
        float eo[4];
        #pragma unroll
        for (int k = 0; k < 4; ++k) {
            int i = ia[k], j = ja[k];
            unsigned int wi = s_packed[i >> 4], wj = s_packed[j >> 4];
            unsigned int ti = (wi >> ((i & 15) * 2)) & 3u;
            unsigned int tj = (wj >> ((j & 15) * 2)) & 3u;
            int t = (int)((ti << 2) | tj);
            // log-spaced table lookup: branchless, no exp, no rc test
            float kf = __builtin_fmaf(__log2f(ra[k]), TAB_INV, TAB_OFF);
            int ki = (int)kf;
            ki = ki < 0 ? 0 : (ki > 256 ? 256 : ki);
            float frac = kf - (float)ki;
            int base = t * TAB_N + ki;
            float v0 = tabE[base];          // ds_read2_b32 pair
            float v1 = tabE[base + 1];
            eo[k] = __builtin_fmaf(v1 - v0, frac, v0);
        }
        // slot allocation + 4 B record stores
        #pragma unroll
        for (int k = 0; k < 4; ++k) {
            if (eo[k] != 0.0f) {
                int atom = ia[k];
                int s = atom >> SB_BITS;
                int slot = atomicAdd(&scnt[s], 1);   // same-bucket lanes -> sequential slots
                if (slot < cap) {
                    unsigned rec = ((__float_as_uint(eo[k]) + 0x2000u) & 0xFFFFC000u)
                                 | (unsigned)(atom & (SBS - 1));
                    regions[(myreg + s) * (size_t)cap + slot] = rec;
                } else {
                    unsafeAtomicAdd(&fallback[atom], eo[k]);   // rare overflow
                }
            }
        }
    }

    // tail (E % 4 != 0): straight to fallback (at most 3 edges)
    if (blockIdx.x == 0) {
        for (int idx = nquad * 4 + threadIdx.x; idx < E; idx += P1_TPB) {
            int i = fa[idx], j = sa[idx];
            unsigned int wi = s_packed[i >> 4], wj = s_packed[j >> 4];
            int t = (int)((((wi >> ((i & 15) * 2)) & 3u) << 2) |
                           ((wj >> ((j & 15) * 2)) & 3u));
            float r = rij[idx];
            float kf = __builtin_fmaf(__log2f(r), TAB_INV, TAB_OFF);
            int ki = (int)kf;
            ki = ki < 0 ? 0 : (ki > 256 ? 256 : ki);
            float frac = kf - (float)ki;
            int base = t * TAB_N + ki;
            float v0 = tabE[base], v1 = tabE[base + 1];
            float e = __builtin_fmaf(v1 - v0, frac, v0);
            if (e != 0.0f) unsafeAtomicAdd(&fallback[i], e);
        }
    }

    __syncthreads();
    if (cap > 0 && threadIdx.x < NS)
        counts[threadIdx.x * P1_BLOCKS + blockIdx.x] = min(scnt[threadIdx.x], cap);
}

// ------- Phase 2: (super-bucket, replica) -> 64 KB LDS accumulator -------
// Wave-parallel over producers: each wave streams its own region independently.
__global__ __launch_bounds__(P2_TPB) void zbl_agg(
    const unsigned int* __restrict__ regions,
    const int*  __restrict__ counts,     // [NS][P1_BLOCKS]
    float* __restrict__ partials,        // [NS][R_SUB][SBS]
    int NS, int cap)
{
    __shared__ float acc[SBS];           // 64 KB -> 2 co-residable blocks/CU
    int s = blockIdx.x;                  // super-bucket
    int r = blockIdx.y;                  // replica
    for (int i = threadIdx.x; i < SBS; i += P2_TPB) acc[i] = 0.0f;
    __syncthreads();

    int wave = threadIdx.x >> 6;
    int lane = threadIdx.x & 63;
    const int NW = P2_TPB >> 6;          // 16 waves
    for (int p = r + wave * R_SUB; p < P1_BLOCKS; p += NW * R_SUB) {
        int n = counts[s * P1_BLOCKS + p];               // wave-uniform load
        size_t base = ((size_t)p * NS + s) * (size_t)cap;
        for (int t = lane; t < n; t += 64) {
            unsigned rec = regions[base + t];            // coalesced 256 B/wave
            atomicAdd(&acc[rec & (SBS - 1)],
                      __uint_as_float(rec & 0xFFFFC000u));   // ds_add_f32
        }
    }
    __syncthreads();

    float* dst = partials + ((size_t)s * R_SUB + r) * SBS;
    for (int i = threadIdx.x; i < SBS; i += P2_TPB)
        dst[i] = acc[i];                                 // plain coalesced stores
}

// ------- Phase 3: reduce R_SUB partials + fallback -> out -------
__global__ __launch_bounds__(TPB_RED) void zbl_red(
    const float* __restrict__ partials,
    const float* __restrict__ fallback,
    float* __restrict__ out,
    int natoms)
{
    int atom = blockIdx.x * TPB_RED + threadIdx.x;
    if (atom >= natoms) return;
    int s = atom >> SB_BITS, i = atom & (SBS - 1);
    float acc = fallback[atom];
    const float* p = partials + (size_t)s * R_SUB * SBS + i;
    #pragma unroll
    for (int k = 0; k < R_SUB; ++k) acc += p[(size_t)k * SBS];
    out[atom] = acc;
}

extern "C" void kernel_launch(void* const* d_in, const int* in_sizes, int n_in,
                              void* d_out, int out_size, void* d_ws, size_t ws_size,
                              hipStream_t stream) {
    const float* rij  = (const float*)d_in[0];
    const float* rcov = (const float*)d_in[1];
    const float* znum = (const float*)d_in[2];
    const int*   fa   = (const int*)d_in[3];
    const int*   sa   = (const int*)d_in[4];
    const int*   types= (const int*)d_in[5];
    float* out = (float*)d_out;
    int E = in_sizes[0];
    int natoms = out_size;
    int nquad = E / 4;
    int nwords = (natoms + 15) / 16;
    int NS = (natoms + SBS - 1) >> SB_BITS;      // 13 for 200K atoms
    if (NS > NS_MAX) NS = NS_MAX;                // (natoms <= 256K)
    int chunkQ = (nquad + P1_BLOCKS - 1) / P1_BLOCKS;

    // ws layout: [packed][counts][fallback][partials][regions...]
    size_t packed_bytes = ((size_t)nwords * 4 + 255) & ~(size_t)255;
    size_t cnt_bytes    = ((size_t)NS * P1_BLOCKS * 4 + 255) & ~(size_t)255;
    size_t fb_bytes     = ((size_t)natoms * 4 + 255) & ~(size_t)255;
    size_t part_bytes   = ((size_t)NS * R_SUB * SBS * 4 + 255) & ~(size_t)255;
    unsigned int* packed = (unsigned int*)d_ws;
    int*   counts   = (int*)  ((char*)d_ws + packed_bytes);
    float* fallback = (float*)((char*)d_ws + packed_bytes + cnt_bytes);
    float* partials = (float*)((char*)d_ws + packed_bytes + cnt_bytes + fb_bytes);
    unsigned int* regions = (unsigned int*)((char*)d_ws + packed_bytes + cnt_bytes
                                            + fb_bytes + part_bytes);

    long long avail = (long long)ws_size
                    - (long long)(packed_bytes + cnt_bytes + fb_bytes + part_bytes);
    int cap = 0;
    if (avail > 0) cap = (int)(avail / ((long long)P1_BLOCKS * (long long)NS * 4));
    if (cap > CAP_MAX) cap = CAP_MAX;

    size_t smem = (size_t)nwords * sizeof(unsigned int);

    if (cap >= 64) {
        zbl_pack<<<96, TPB_PACK, 0, stream>>>(types, packed, fallback, natoms, nwords);
        zbl_bin<<<P1_BLOCKS, P1_TPB, smem, stream>>>(
            rij, rcov, znum, fa, sa, packed, regions, counts, fallback,
            E, nquad, natoms, nwords, NS, cap, chunkQ);
        dim3 g2(NS, R_SUB);
        zbl_agg<<<g2, P2_TPB, 0, stream>>>(regions, counts, partials, NS, cap);
        zbl_red<<<(natoms + TPB_RED - 1) / TPB_RED, TPB_RED, 0, stream>>>(
            partials, fallback, out, natoms);
    } else {
        // ws too small: everything overflows straight into out (correct, slow)
        zbl_pack<<<96, TPB_PACK, 0, stream>>>(types, packed, out, natoms, nwords);
        zbl_bin<<<P1_BLOCKS, P1_TPB, smem, stream>>>(
            rij, rcov, znum, fa, sa, packed, regions, counts, out,
            E, nquad, natoms, nwords, NS, 0, chunkQ);
    }
}

// Round 14
// 164.470 us; speedup vs baseline: 1.0841x; 1.0841x over previous
//
#include <hip/hip_runtime.h>

#define TPB_PACK  256
#define P1_BLOCKS 512
#define P1_TPB    1024
#define SB_BITS   14
#define SBS       (1 << SB_BITS)     // atoms per super-bucket (16384)
#define NS_MAX    16
#define P2_TPB    1024
#define R_SUB     39                 // 13*39=507 blocks: each wave owns <=1 producer,
                                     // ~2 blocks/CU -> max concurrent latency chains.
                                     // (R13: R_SUB=20 regressed agg 10->43 us — latency-bound!)
#define TPB_RED   256
#define CAP_MAX   1024

// log-spaced energy table: r = 2^(L0 + k*HL), k in [0,256]; 258 entries/type (pad)
#define TAB_N   258
#define TAB_L0  (-3.3219281f)        // log2(0.1)
#define TAB_HL  (0.017157490f)       // (log2(2.1)-log2(0.1))/256
#define TAB_INV (58.283567f)         // 1/TAB_HL
#define TAB_OFF (193.61423f)         // -L0*TAB_INV

// ---- pack atom types (2 bits each) AND zero the fallback accumulator ----
__global__ __launch_bounds__(TPB_PACK) void zbl_pack(
    const int* __restrict__ types, unsigned int* __restrict__ packed,
    float* __restrict__ fallback, int natoms, int nwords)
{
    int tid = blockIdx.x * TPB_PACK + threadIdx.x;
    int nth = gridDim.x * TPB_PACK;
    for (int w = tid; w < nwords; w += nth) {
        int base = w << 4;
        unsigned int word = 0;
        #pragma unroll
        for (int j = 0; j < 16; ++j) {
            int i = base + j;
            unsigned int t = (i < natoms) ? (unsigned int)types[i] : 0u;
            word |= (t & 3u) << (2 * j);
        }
        packed[w] = word;
    }
    for (int i = tid; i < natoms; i += nth) fallback[i] = 0.0f;
}

// ------- Phase 1: tabulated e(r,t); per-lane binning into NS coarse buckets -------
// 4 B records: f32 e with low 14 mantissa bits (rounded away) replaced by the
// atom index within the super-bucket. Exponent untouched -> e!=0 gate and
// in-bucket index both survive; rel err 2^-10.
__global__ __launch_bounds__(P1_TPB) void zbl_bin(
    const float* __restrict__ rij,
    const float* __restrict__ rcov,
    const float* __restrict__ znum,
    const int*  __restrict__ fa,
    const int*  __restrict__ sa,
    const unsigned int* __restrict__ packed,
    unsigned int* __restrict__ regions,  // [P1_BLOCKS][NS][cap] 4 B records
    int*   __restrict__ counts,          // [NS][P1_BLOCKS] (transposed)
    float* __restrict__ fallback,        // natoms floats, pre-zeroed (= d_out if cap==0)
    int E, int nquad, int natoms, int nwords, int NS, int cap, int chunkQ)
{
    extern __shared__ unsigned int s_packed[];   // nwords words (~50 KB)
    __shared__ float  tabE[16 * TAB_N];          // 16.5 KB energy table
    __shared__ float4 cB[16];                    // {rc, f/2, A/6, B/8}
    __shared__ float4 cS[16];                    // exp2 slopes
    __shared__ float  cC[16];                    // C/2
    __shared__ int scnt[NS_MAX];

    for (int w = threadIdx.x; w < nwords; w += P1_TPB)
        s_packed[w] = packed[w];                 // coalesced, L2-resident
    if (threadIdx.x < NS) scnt[threadIdx.x] = 0;

    if (threadIdx.x < 16) {
        const float cc[4] = {0.02817f, 0.28022f, 0.50986f, 0.18175f};
        const float dd[4] = {0.20162f, 0.4029f, 0.94229f, 3.1998f};
        const float COUL = 14.399645478425668f;
        int t = threadIdx.x;
        int ti = t >> 2, tj = t & 3;
        float zi = znum[ti], zj = znum[tj];
        float rc = rcov[ti] + rcov[tj];
        float a = 0.4685f / (powf(zi, 0.23f) + powf(zj, 0.23f));
        float inva = 1.0f / a;
        float factor = COUL * zi * zj;
        float da[4], ee[4];
        float phi = 0.0f, dphi = 0.0f, d2phi = 0.0f;
        #pragma unroll
        for (int k = 0; k < 4; ++k) {
            da[k] = dd[k] * inva;
            ee[k] = expf(-rc * da[k]);
            phi   += cc[k] * ee[k];
            dphi  -= cc[k] * da[k] * ee[k];
            d2phi += cc[k] * da[k] * da[k] * ee[k];
        }
        float invrc = 1.0f / rc;
        float ec   = factor * invrc * phi;
        float dec  = factor * invrc * (-phi * invrc + dphi);
        float d2ec = factor * invrc * (d2phi - 2.0f * invrc * dphi + 2.0f * phi * invrc * invrc);
        float A = (-3.0f * dec + rc * d2ec) * invrc * invrc;
        float B = (2.0f * dec - rc * d2ec) * invrc * invrc * invrc;
        float Cc = -ec + 0.5f * rc * dec - rc * rc * d2ec * (1.0f / 12.0f);
        const float L2E = 1.4426950408889634f;
        cB[t] = make_float4(rc, 0.5f * factor, A * (1.0f / 6.0f), B * 0.125f);
        cS[t] = make_float4(-da[0] * L2E, -da[1] * L2E, -da[2] * L2E, -da[3] * L2E);
        cC[t] = Cc * 0.5f;
    }
    __syncthreads();

    const float lc0 = -5.1497481f;   // log2(0.02817)
    const float lc1 = -1.8353434f;   // log2(0.28022)
    const float lc2 = -0.9718340f;   // log2(0.50986)
    const float lc3 = -2.4600449f;   // log2(0.18175)

    // build the per-type energy table (once per block)
    for (int n = threadIdx.x; n < 16 * TAB_N; n += P1_TPB) {
        int t = n / TAB_N, k = n - t * TAB_N;
        float v = 0.0f;
        if (k <= 256) {
            float r = exp2f(__builtin_fmaf((float)k, TAB_HL, TAB_L0));
            float4 B = cB[t];
            if (r <= B.x) {
                float4 S = cS[t];
                float p = exp2f(__builtin_fmaf(r, S.x, lc0))
                        + exp2f(__builtin_fmaf(r, S.y, lc1))
                        + exp2f(__builtin_fmaf(r, S.z, lc2))
                        + exp2f(__builtin_fmaf(r, S.w, lc3));
                float r3 = r * r * r;
                float poly = __builtin_fmaf(__builtin_fmaf(B.w, r, B.z), r3, cC[t]);
                v = __builtin_fmaf(B.y * p, 1.0f / r, poly);
            }
        }
        tabE[n] = v;
    }
    __syncthreads();

    const float4* rij4 = (const float4*)rij;
    const int4*   fa4  = (const int4*)fa;
    const int4*   sa4  = (const int4*)sa;

    size_t myreg = (size_t)blockIdx.x * NS;

    int q0 = blockIdx.x * chunkQ;
    int q1 = q0 + chunkQ; if (q1 > nquad) q1 = nquad;

    for (int q = q0 + threadIdx.x; q < q1; q += P1_TPB) {
        float4 rv = rij4[q];
        int4   iv = fa4[q];
        int4   jv = sa4[q];
        float ra[4] = {rv.x, rv.y, rv.z, rv.w};
        int   ia[4] = {iv.x, iv.y, iv.z, iv.w};
        int   ja[4] = {jv.x, jv.y, jv.z, jv.w};
        float eo[4];
        #pragma unroll
        for (int k = 0; k < 4; ++k) {
            int i = ia[k], j = ja[k];
            unsigned int wi = s_packed[i >> 4], wj = s_packed[j >> 4];
            unsigned int ti = (wi >> ((i & 15) * 2)) & 3u;
            unsigned int tj = (wj >> ((j & 15) * 2)) & 3u;
            int t = (int)((ti << 2) | tj);
            // log-spaced table lookup: branchless, no exp, no rc test
            float kf = __builtin_fmaf(__log2f(ra[k]), TAB_INV, TAB_OFF);
            int ki = (int)kf;
            ki = ki < 0 ? 0 : (ki > 256 ? 256 : ki);
            float frac = kf - (float)ki;
            int base = t * TAB_N + ki;
            float v0 = tabE[base];          // ds_read2_b32 pair
            float v1 = tabE[base + 1];
            eo[k] = __builtin_fmaf(v1 - v0, frac, v0);
        }
        // slot allocation + 4 B record stores
        #pragma unroll
        for (int k = 0; k < 4; ++k) {
            if (eo[k] != 0.0f) {
                int atom = ia[k];
                int s = atom >> SB_BITS;
                int slot = atomicAdd(&scnt[s], 1);   // same-bucket lanes -> sequential slots
                if (slot < cap) {
                    unsigned rec = ((__float_as_uint(eo[k]) + 0x2000u) & 0xFFFFC000u)
                                 | (unsigned)(atom & (SBS - 1));
                    regions[(myreg + s) * (size_t)cap + slot] = rec;
                } else {
                    unsafeAtomicAdd(&fallback[atom], eo[k]);   // rare overflow
                }
            }
        }
    }

    // tail (E % 4 != 0): straight to fallback (at most 3 edges)
    if (blockIdx.x == 0) {
        for (int idx = nquad * 4 + threadIdx.x; idx < E; idx += P1_TPB) {
            int i = fa[idx], j = sa[idx];
            unsigned int wi = s_packed[i >> 4], wj = s_packed[j >> 4];
            int t = (int)((((wi >> ((i & 15) * 2)) & 3u) << 2) |
                           ((wj >> ((j & 15) * 2)) & 3u));
            float r = rij[idx];
            float kf = __builtin_fmaf(__log2f(r), TAB_INV, TAB_OFF);
            int ki = (int)kf;
            ki = ki < 0 ? 0 : (ki > 256 ? 256 : ki);
            float frac = kf - (float)ki;
            int base = t * TAB_N + ki;
            float v0 = tabE[base], v1 = tabE[base + 1];
            float e = __builtin_fmaf(v1 - v0, frac, v0);
            if (e != 0.0f) unsafeAtomicAdd(&fallback[i], e);
        }
    }

    __syncthreads();
    if (cap > 0 && threadIdx.x < NS)
        counts[threadIdx.x * P1_BLOCKS + blockIdx.x] = min(scnt[threadIdx.x], cap);
}

// ------- Phase 2: (super-bucket, replica) -> 64 KB LDS accumulator -------
// Wave-parallel over producers: each wave streams its own region independently.
__global__ __launch_bounds__(P2_TPB) void zbl_agg(
    const unsigned int* __restrict__ regions,
    const int*  __restrict__ counts,     // [NS][P1_BLOCKS]
    float* __restrict__ partials,        // [NS][R_SUB][SBS]
    int NS, int cap)
{
    __shared__ float acc[SBS];           // 64 KB -> 2 blocks/CU
    int s = blockIdx.x;                  // super-bucket
    int r = blockIdx.y;                  // replica

    // vectorized zero-init: 4 consecutive floats/thread -> b128 ds writes
    float4* acc4 = (float4*)acc;
    for (int i = threadIdx.x; i < SBS / 4; i += P2_TPB)
        acc4[i] = make_float4(0.f, 0.f, 0.f, 0.f);
    __syncthreads();

    int wave = threadIdx.x >> 6;
    int lane = threadIdx.x & 63;
    const int NW = P2_TPB >> 6;          // 16 waves
    for (int p = r + wave * R_SUB; p < P1_BLOCKS; p += NW * R_SUB) {
        int n = counts[s * P1_BLOCKS + p];               // wave-uniform load
        size_t base = ((size_t)p * NS + s) * (size_t)cap;
        for (int t = lane; t < n; t += 64) {
            unsigned rec = regions[base + t];            // coalesced 256 B/wave
            atomicAdd(&acc[rec & (SBS - 1)],
                      __uint_as_float(rec & 0xFFFFC000u));   // ds_add_f32
        }
    }
    __syncthreads();

    // vectorized dump: b128 ds reads + dwordx4 global stores
    float4* dst4 = (float4*)(partials + ((size_t)s * R_SUB + r) * SBS);
    for (int i = threadIdx.x; i < SBS / 4; i += P2_TPB)
        dst4[i] = acc4[i];
}

// ------- Phase 3: reduce R_SUB partials + fallback -> out (float4 lanes) -------
__global__ __launch_bounds__(TPB_RED) void zbl_red(
    const float* __restrict__ partials,
    const float* __restrict__ fallback,
    float* __restrict__ out,
    int natoms)
{
    int q = blockIdx.x * TPB_RED + threadIdx.x;      // quad-of-atoms index
    int nq = natoms >> 2;
    if (q < nq) {
        int atom = q << 2;
        int s = atom >> SB_BITS, i = atom & (SBS - 1);   // SBS%4==0: quad never crosses buckets
        const float4* fb4 = (const float4*)(fallback + atom);
        float4 acc = *fb4;
        const float* p = partials + (size_t)s * R_SUB * SBS + i;
        #pragma unroll
        for (int k = 0; k < R_SUB; ++k) {
            float4 v = *(const float4*)(p + (size_t)k * SBS);
            acc.x += v.x; acc.y += v.y; acc.z += v.z; acc.w += v.w;
        }
        *(float4*)(out + atom) = acc;
    }
    // scalar tail (natoms % 4)
    if (blockIdx.x == 0 && threadIdx.x < (natoms & 3)) {
        int atom = (nq << 2) + threadIdx.x;
        int s = atom >> SB_BITS, i = atom & (SBS - 1);
        float acc = fallback[atom];
        const float* p = partials + (size_t)s * R_SUB * SBS + i;
        #pragma unroll
        for (int k = 0; k < R_SUB; ++k) acc += p[(size_t)k * SBS];
        out[atom] = acc;
    }
}

extern "C" void kernel_launch(void* const* d_in, const int* in_sizes, int n_in,
                              void* d_out, int out_size, void* d_ws, size_t ws_size,
                              hipStream_t stream) {
    const float* rij  = (const float*)d_in[0];
    const float* rcov = (const float*)d_in[1];
    const float* znum = (const float*)d_in[2];
    const int*   fa   = (const int*)d_in[3];
    const int*   sa   = (const int*)d_in[4];
    const int*   types= (const int*)d_in[5];
    float* out = (float*)d_out;
    int E = in_sizes[0];
    int natoms = out_size;
    int nquad = E / 4;
    int nwords = (natoms + 15) / 16;
    int NS = (natoms + SBS - 1) >> SB_BITS;      // 13 for 200K atoms
    if (NS > NS_MAX) NS = NS_MAX;                // (natoms <= 256K)
    int chunkQ = (nquad + P1_BLOCKS - 1) / P1_BLOCKS;

    // ws layout: [packed][counts][fallback][partials][regions...]
    size_t packed_bytes = ((size_t)nwords * 4 + 255) & ~(size_t)255;
    size_t cnt_bytes    = ((size_t)NS * P1_BLOCKS * 4 + 255) & ~(size_t)255;
    size_t fb_bytes     = ((size_t)natoms * 4 + 255) & ~(size_t)255;
    size_t part_bytes   = ((size_t)NS * R_SUB * SBS * 4 + 255) & ~(size_t)255;
    unsigned int* packed = (unsigned int*)d_ws;
    int*   counts   = (int*)  ((char*)d_ws + packed_bytes);
    float* fallback = (float*)((char*)d_ws + packed_bytes + cnt_bytes);
    float* partials = (float*)((char*)d_ws + packed_bytes + cnt_bytes + fb_bytes);
    unsigned int* regions = (unsigned int*)((char*)d_ws + packed_bytes + cnt_bytes
                                            + fb_bytes + part_bytes);

    long long avail = (long long)ws_size
                    - (long long)(packed_bytes + cnt_bytes + fb_bytes + part_bytes);
    int cap = 0;
    if (avail > 0) cap = (int)(avail / ((long long)P1_BLOCKS * (long long)NS * 4));
    if (cap > CAP_MAX) cap = CAP_MAX;

    size_t smem = (size_t)nwords * sizeof(unsigned int);

    if (cap >= 64) {
        zbl_pack<<<96, TPB_PACK, 0, stream>>>(types, packed, fallback, natoms, nwords);
        zbl_bin<<<P1_BLOCKS, P1_TPB, smem, stream>>>(
            rij, rcov, znum, fa, sa, packed, regions, counts, fallback,
            E, nquad, natoms, nwords, NS, cap, chunkQ);
        dim3 g2(NS, R_SUB);
        zbl_agg<<<g2, P2_TPB, 0, stream>>>(regions, counts, partials, NS, cap);
        int nq = natoms >> 2;
        zbl_red<<<(nq + TPB_RED - 1) / TPB_RED, TPB_RED, 0, stream>>>(
            partials, fallback, out, natoms);
    } else {
        // ws too small: everything overflows straight into out (correct, slow)
        zbl_pack<<<96, TPB_PACK, 0, stream>>>(types, packed, out, natoms, nwords);
        zbl_bin<<<P1_BLOCKS, P1_TPB, smem, stream>>>(
            rij, rcov, znum, fa, sa, packed, regions, counts, out,
            E, nquad, natoms, nwords, NS, 0, chunkQ);
    }
}